// Round 19
// baseline (3506.082 us; speedup 1.0000x reference)
//
#include <hip/hip_runtime.h>
#include <hip/hip_bf16.h>
#include <cstddef>

#define NB 4
#define NL 4096
#define ND 1024
#define NH 4
#define NDK 256
#define NCH 128

typedef __hip_bfloat16 bf16;
typedef __attribute__((ext_vector_type(8))) short bf16x8;
typedef __attribute__((ext_vector_type(4))) float f32x4;

__device__ __forceinline__ float sigf(float x){ return 1.0f/(1.0f + expf(-x)); }
__device__ __forceinline__ float geluf(float x){ return 0.5f*x*(1.0f+erff(x*0.70710678118654752f)); }
__device__ __forceinline__ float us2f(unsigned short s){ return __uint_as_float(((unsigned int)s)<<16); }
__device__ __forceinline__ float b2f(bf16 x){ return __bfloat162float(x); }
__device__ __forceinline__ bf16  f2b(float x){ return __float2bfloat16(x); }
__device__ __forceinline__ unsigned short f2bu(float x){ bf16 h = f2b(x); return *(unsigned short*)&h; }

__device__ __forceinline__ float4 ld4f(const float* p){ return *(const float4*)p; }
__device__ __forceinline__ float4 ld4f(const bf16* p){
    ushort4 u = *(const ushort4*)p;
    return make_float4(us2f(u.x), us2f(u.y), us2f(u.z), us2f(u.w));
}
__device__ __forceinline__ void st4(float* p, float4 v){ *(float4*)p = v; }
__device__ __forceinline__ void st4(bf16* p, float4 v){
    bf16 a=f2b(v.x), b=f2b(v.y), c=f2b(v.z), d=f2b(v.w);
    ushort4 u;
    u.x=*(unsigned short*)&a; u.y=*(unsigned short*)&b;
    u.z=*(unsigned short*)&c; u.w=*(unsigned short*)&d;
    *(ushort4*)p = u;
}

#define DOT4(v, s) ((v).x*(s).x + (v).y*(s).y + (v).z*(s).z + (v).w*(s).w)

// ---------------- MFMA GEMM with split-bf16 precision ----------------
// WS=1: W split hi+lo (2 W-products); WS=0: W hi only (1 product). X f32 adds xl*bh.
template<typename XT, int ACT, int WS, typename CT>
__global__ __launch_bounds__(256) void gemm_mfma(const XT* __restrict__ X,
    const float* __restrict__ W, const float* __restrict__ bias,
    CT* __restrict__ C, int M, int N, int K)
{
    constexpr int SX = (sizeof(XT)==4) ? 1 : 0;
    __shared__ unsigned short Ah[128*40];
    __shared__ unsigned short Al[SX ? 128*40 : 8];
    __shared__ unsigned short Bh[128*40];
    __shared__ unsigned short Bl[WS ? 128*40 : 8];
    const int t = threadIdx.x;
    const int wid = t >> 6, l = t & 63;
    const int wr = wid >> 1, wc = wid & 1;
    const int bm = blockIdx.y*128, bn = blockIdx.x*128;
    const int sr = t >> 1, sk = (t & 1)*16;
    const XT* Xb = X + (size_t)(bm+sr)*K + sk;
    const float* Wb = W + (size_t)(bn+sr)*K + sk;
    const int lr = l & 15, lk = (l >> 4)*8;
    f32x4 acc[4][4];
    #pragma unroll
    for (int i=0;i<4;i++)
        #pragma unroll
        for (int j=0;j<4;j++) acc[i][j] = (f32x4){0.f,0.f,0.f,0.f};

    for (int kt = 0; kt < K; kt += 32) {
        unsigned short hx[16], lx[16], hw[16], lw[16];
        {
            float wf[16];
            *(float4*)&wf[0]  = ld4f(Wb + kt);
            *(float4*)&wf[4]  = ld4f(Wb + kt + 4);
            *(float4*)&wf[8]  = ld4f(Wb + kt + 8);
            *(float4*)&wf[12] = ld4f(Wb + kt + 12);
            #pragma unroll
            for (int j=0;j<16;j++){
                bf16 h = f2b(wf[j]);
                hw[j] = *(unsigned short*)&h;
                if (WS) lw[j] = f2bu(wf[j] - b2f(h));
            }
        }
        if constexpr (SX){
            float xf[16];
            *(float4*)&xf[0]  = ld4f(Xb + kt);
            *(float4*)&xf[4]  = ld4f(Xb + kt + 4);
            *(float4*)&xf[8]  = ld4f(Xb + kt + 8);
            *(float4*)&xf[12] = ld4f(Xb + kt + 12);
            #pragma unroll
            for (int j=0;j<16;j++){
                bf16 h = f2b(xf[j]);
                hx[j] = *(unsigned short*)&h;
                lx[j] = f2bu(xf[j] - b2f(h));
            }
        } else {
            *(uint4*)&hx[0] = *(const uint4*)(Xb + kt);
            *(uint4*)&hx[8] = *(const uint4*)(Xb + kt + 8);
        }
        __syncthreads();
        *(uint4*)&Ah[sr*40 + sk]     = *(uint4*)&hx[0];
        *(uint4*)&Ah[sr*40 + sk + 8] = *(uint4*)&hx[8];
        if constexpr (SX){
            *(uint4*)&Al[sr*40 + sk]     = *(uint4*)&lx[0];
            *(uint4*)&Al[sr*40 + sk + 8] = *(uint4*)&lx[8];
        }
        *(uint4*)&Bh[sr*40 + sk]     = *(uint4*)&hw[0];
        *(uint4*)&Bh[sr*40 + sk + 8] = *(uint4*)&hw[8];
        if constexpr (WS){
            *(uint4*)&Bl[sr*40 + sk]     = *(uint4*)&lw[0];
            *(uint4*)&Bl[sr*40 + sk + 8] = *(uint4*)&lw[8];
        }
        __syncthreads();
        bf16x8 ah[4], al[4];
        #pragma unroll
        for (int mi=0;mi<4;mi++){
            ah[mi] = *(const bf16x8*)&Ah[(wr*64 + mi*16 + lr)*40 + lk];
            if constexpr (SX) al[mi] = *(const bf16x8*)&Al[(wr*64 + mi*16 + lr)*40 + lk];
        }
        #pragma unroll
        for (int nj=0;nj<4;nj++){
            bf16x8 bh = *(const bf16x8*)&Bh[(wc*64 + nj*16 + lr)*40 + lk];
            bf16x8 bl;
            if constexpr (WS) bl = *(const bf16x8*)&Bl[(wc*64 + nj*16 + lr)*40 + lk];
            #pragma unroll
            for (int mi=0;mi<4;mi++){
                acc[mi][nj] = __builtin_amdgcn_mfma_f32_16x16x32_bf16(ah[mi], bh, acc[mi][nj], 0,0,0);
                if constexpr (WS)
                    acc[mi][nj] = __builtin_amdgcn_mfma_f32_16x16x32_bf16(ah[mi], bl, acc[mi][nj], 0,0,0);
                if constexpr (SX)
                    acc[mi][nj] = __builtin_amdgcn_mfma_f32_16x16x32_bf16(al[mi], bh, acc[mi][nj], 0,0,0);
            }
        }
    }
    const int cr0 = (l >> 4) * 4;
    #pragma unroll
    for (int nj=0;nj<4;nj++){
        const int col = bn + wc*64 + nj*16 + lr;
        const float bv = bias ? bias[col] : 0.f;
        #pragma unroll
        for (int mi=0;mi<4;mi++){
            const int m0 = bm + wr*64 + mi*16 + cr0;
            #pragma unroll
            for (int r=0;r<4;r++){
                float v = acc[mi][nj][r] + bv;
                if (ACT==1) v = geluf(v);
                if constexpr (sizeof(CT)==2) C[(size_t)(m0+r)*N + col] = f2b(v);
                else                         C[(size_t)(m0+r)*N + col] = v;
            }
        }
    }
}

// ---------------- filter transpose: f[c][k] -> ft[k][c] ----------------
__global__ __launch_bounds__(256) void ftrans_kernel(const float* __restrict__ f,
    float* __restrict__ ft, int K)
{
    int idx = blockIdx.x*256 + threadIdx.x;
    if (idx < ND*K){
        int c = idx / K, k = idx - c*K;
        ft[k*ND + c] = f[idx];
    }
}

// ---------------- depthwise causal conv: reg sliding window, 8 rows x 8 ch / thread ----------------
template<int K, int ACT>
__global__ __launch_bounds__(256) void dwconv3_kernel(const bf16* __restrict__ x,
    const float* __restrict__ ft, bf16* __restrict__ y)
{
    const int tr = threadIdx.x >> 7;
    const int c8 = (threadIdx.x & 127) * 8;
    const long row0 = (long)blockIdx.x * 16 + tr * 8;
    const int l0 = (int)(row0 & (NL - 1));
    const long bbase = row0 - l0;
    float xw[8][8];
    float acc[8][8];
    #pragma unroll
    for (int r=0;r<8;r++)
        #pragma unroll
        for (int j=0;j<8;j++) acc[r][j] = 0.f;
    #pragma unroll
    for (int w2=0;w2<8;w2++){
        int ls = l0 - (K-1) + w2;
        if (ls >= 0){
            const bf16* p = x + (bbase + ls)*ND + c8;
            ushort4 lo = *(const ushort4*)p;
            ushort4 hi = *(const ushort4*)(p + 4);
            xw[w2][0]=us2f(lo.x); xw[w2][1]=us2f(lo.y); xw[w2][2]=us2f(lo.z); xw[w2][3]=us2f(lo.w);
            xw[w2][4]=us2f(hi.x); xw[w2][5]=us2f(hi.y); xw[w2][6]=us2f(hi.z); xw[w2][7]=us2f(hi.w);
        } else {
            #pragma unroll
            for (int j=0;j<8;j++) xw[w2][j]=0.f;
        }
    }
    #pragma unroll
    for (int tt=0;tt<K;tt++){
        float4 f0 = *(const float4*)(ft + (size_t)tt*ND + c8);
        float4 f1 = *(const float4*)(ft + (size_t)tt*ND + c8 + 4);
        float fv[8] = {f0.x,f0.y,f0.z,f0.w,f1.x,f1.y,f1.z,f1.w};
        #pragma unroll
        for (int r=0;r<8;r++){
            const int sl = (tt + r) & 7;
            #pragma unroll
            for (int j=0;j<8;j++) acc[r][j] += xw[sl][j]*fv[j];
        }
        if (tt < K-1){
            const int sl = tt & 7;
            int ls = l0 - (K-1) + tt + 8;
            if (ls >= 0){
                const bf16* p = x + (bbase + ls)*ND + c8;
                ushort4 lo = *(const ushort4*)p;
                ushort4 hi = *(const ushort4*)(p + 4);
                xw[sl][0]=us2f(lo.x); xw[sl][1]=us2f(lo.y); xw[sl][2]=us2f(lo.z); xw[sl][3]=us2f(lo.w);
                xw[sl][4]=us2f(hi.x); xw[sl][5]=us2f(hi.y); xw[sl][6]=us2f(hi.z); xw[sl][7]=us2f(hi.w);
            } else {
                #pragma unroll
                for (int j=0;j<8;j++) xw[sl][j]=0.f;
            }
        }
    }
    #pragma unroll
    for (int r=0;r<8;r++){
        bf16* yp = y + (bbase + l0 + r)*ND + c8;
        float o[8];
        #pragma unroll
        for (int j=0;j<8;j++){
            float v = acc[r][j];
            if (ACT) v = v * sigf(v);
            o[j] = v;
        }
        st4(yp,   make_float4(o[0],o[1],o[2],o[3]));
        st4(yp+4, make_float4(o[4],o[5],o[6],o[7]));
    }
}

// ---------------- beta = sigmoid(hs @ Wb^T) ----------------
__global__ __launch_bounds__(256) void beta_kernel(const float* __restrict__ hs,
    const float* __restrict__ Wb, float* __restrict__ beta)
{
    const int wid = (int)((blockIdx.x*256 + threadIdx.x) >> 6);
    const int lane = threadIdx.x & 63;
    const int h = wid & 3, row = wid >> 2;
    const float* x = hs + (size_t)row*ND;
    const float* w = Wb + (size_t)h*ND;
    float s = 0.f;
    for (int i = lane; i < ND; i += 64) s += x[i]*w[i];
    #pragma unroll
    for (int o=32;o>0;o>>=1) s += __shfl_xor(s,o);
    if (lane == 0) beta[(size_t)row*NH + h] = sigf(s);
}

// ---------------- l2norm q,k in place ----------------
__global__ __launch_bounds__(256) void prep_kernel(bf16* __restrict__ q, bf16* __restrict__ k)
{
    const int row = blockIdx.x;
    const int h = threadIdx.x >> 6, lane = threadIdx.x & 63;
    const size_t off = (size_t)row*ND + h*NDK + lane*4;
    float4 q4 = ld4f(q + off);
    float4 k4 = ld4f(k + off);
    float sq = q4.x*q4.x+q4.y*q4.y+q4.z*q4.z+q4.w*q4.w;
    float sk = k4.x*k4.x+k4.y*k4.y+k4.z*k4.z+k4.w*k4.w;
    #pragma unroll
    for (int o=32;o>0;o>>=1){ sq += __shfl_xor(sq,o); sk += __shfl_xor(sk,o); }
    float rq = rsqrtf(sq + 1e-6f), rk = rsqrtf(sk + 1e-6f);
    q4.x*=rq; q4.y*=rq; q4.z*=rq; q4.w*=rq;
    k4.x*=rk; k4.y*=rk; k4.z*=rk; k4.w*=rk;
    st4(q + off, q4);
    st4(k + off, k4);
}

// ---------------- UT transform per (b,h,chunk) ----------------
__global__ __launch_bounds__(256) void ut_kernel(const bf16* __restrict__ qn,
    const bf16* __restrict__ kn, const bf16* __restrict__ vv,
    const float* __restrict__ beta, bf16* __restrict__ u_,
    bf16* __restrict__ w_, bf16* __restrict__ attn)
{
    __shared__ float ks[32][257];
    __shared__ float qs[32][257];
    __shared__ float dkk[32][33];
    __shared__ float Ti[32][33];
    __shared__ float bs[32];
    const int blk = blockIdx.x;
    const int n = blk & (NCH-1), bh = blk >> 7;
    const int b = bh >> 2, h = bh & 3;
    const int t = threadIdx.x;
    const size_t base = ((size_t)b*NL + n*32)*ND + h*NDK;
    #pragma unroll
    for (int r=0;r<8;r++){
        int idx = t + (r<<8);
        int i = idx >> 6, dp = (idx & 63) << 2;
        float4 kv = ld4f(kn + base + (size_t)i*ND + dp);
        ks[i][dp]=kv.x; ks[i][dp+1]=kv.y; ks[i][dp+2]=kv.z; ks[i][dp+3]=kv.w;
        float4 qv = ld4f(qn + base + (size_t)i*ND + dp);
        qs[i][dp]=qv.x; qs[i][dp+1]=qv.y; qs[i][dp+2]=qv.z; qs[i][dp+3]=qv.w;
    }
    if (t < 32) bs[t] = beta[((size_t)b*NL + n*32 + t)*NH + h];
    __syncthreads();
    #pragma unroll
    for (int p=0;p<4;p++){
        const int i = (t>>5) + (p<<3), j = t & 31;
        float aK=0.f, aA=0.f;
        for (int d2=0; d2<256; d2++){
            float kj = ks[j][d2];
            aK += ks[i][d2]*kj;
            aA += qs[i][d2]*kj;
        }
        dkk[i][j] = aK;
        attn[((size_t)bh*NCH + n)*1024 + i*32 + j] = f2b((j<=i)? aA : 0.f);
    }
    __syncthreads();
    if (t < 32) Ti[0][t] = (t==0)?1.f:0.f;
    __syncthreads();
    for (int i=1;i<32;i++){
        if (t < 32){
            const int j = t;
            float v;
            if (j > i) v = 0.f;
            else if (j == i) v = 1.f;
            else {
                float acc = 0.f;
                for (int p2=j;p2<i;p2++) acc += dkk[i][p2]*Ti[p2][j];
                v = -bs[i]*acc;
            }
            Ti[i][j] = v;
        }
        __syncthreads();
    }
    {
        float ua[32];
        #pragma unroll
        for (int i=0;i<32;i++) ua[i]=0.f;
        for (int j=0;j<32;j++){
            float vj = b2f(vv[base + (size_t)j*ND + t]) * bs[j];
            #pragma unroll
            for (int i=0;i<32;i++) ua[i] += Ti[i][j]*vj;
        }
        #pragma unroll
        for (int i=0;i<32;i++) u_[base + (size_t)i*ND + t] = f2b(ua[i]);
        #pragma unroll
        for (int i=0;i<32;i++) ua[i]=0.f;
        for (int j=0;j<32;j++){
            float kjv = ks[j][t]*bs[j];
            #pragma unroll
            for (int i=0;i<32;i++) ua[i] += Ti[i][j]*kjv;
        }
        #pragma unroll
        for (int i=0;i<32;i++) w_[base + (size_t)i*ND + t] = f2b(ua[i]);
    }
}

// ---------------- sequential chunk scan: slice 16, 256 WGs x 1024 threads, 4 waves/SIMD ----------------
// __launch_bounds__(1024, 4): min 4 waves/EU -> 1 WG/CU -> VGPR cap 128 (no spills).
__global__ __launch_bounds__(1024, 4) void scan16f_kernel(const bf16* __restrict__ qn,
    const bf16* __restrict__ kn, const bf16* __restrict__ u_,
    const bf16* __restrict__ w_, const bf16* __restrict__ attn,
    bf16* __restrict__ pd)
{
    __shared__ unsigned short bw[32][268];
    __shared__ unsigned short bq[32][268];
    __shared__ unsigned short bk[32][268];
    __shared__ float St[16][260];            // S transposed: [dv_local][dk]
    __shared__ float ual[32][17];            // combined u_adj [c][dv_local]
    __shared__ float uap[4][32][17];         // partials per quarter
    __shared__ float oap[4][32][17];
    __shared__ float atl[32][33];
    const int blk = blockIdx.x;              // 256 WGs
    const int sl = blk >> 4;                 // dv slice 0..15
    const int bh = blk & 15;                 // same-bh WGs share XCD
    const int b = bh >> 2, h = bh & 3;
    const int d0 = sl * 16;
    const int t = threadIdx.x;               // 0..1023
    const int qtr = t >> 8;                  // k-range quarter 0..3
    const int tq = t & 255;
    const int li = tq & 31, dg = tq >> 5;    // phase1: row li, dv cols dg*2, dg*2+1
    const int r1 = (t >> 4) & 31, c1 = t & 15; // combine/phase1b (t<512)
    const int cg = t & 63, dh = (t >> 6) & 15; // update: dk cols cg*4..+3, dv row dh
    for (int i = t; i < 16*260; i += 1024) ((float*)St)[i] = 0.f;
    const bf16* qb = qn + (size_t)b*NL*ND + h*NDK;
    const bf16* kb = kn + (size_t)b*NL*ND + h*NDK;
    const bf16* ub = u_ + (size_t)b*NL*ND + h*NDK;
    const bf16* wb = w_ + (size_t)b*NL*ND + h*NDK;
    const bf16* ab = attn + (size_t)bh*NCH*1024;
    bf16* pdb = pd + (size_t)b*NL*ND + h*NDK + d0;
    for (int n=0;n<NCH;n++){
        const size_t cb = (size_t)n*32*ND;
        __syncthreads();   // prev consumers done before restage
        #pragma unroll
        for (int it=0;it<2;++it){
            int idx = it*1024 + t;
            int row = idx >> 6, c4 = (idx & 63)*4;
            *(ushort4*)&bw[row][c4] = *(const ushort4*)&wb[cb + (size_t)row*ND + c4];
            *(ushort4*)&bq[row][c4] = *(const ushort4*)&qb[cb + (size_t)row*ND + c4];
            *(ushort4*)&bk[row][c4] = *(const ushort4*)&kb[cb + (size_t)row*ND + c4];
        }
        atl[t>>5][t&31] = b2f(ab[(size_t)n*1024 + t]);
        __syncthreads();
        // phase1 partial: quarter qtr -> cgi qtr*16 .. +15 (quarter 0 seeds with u)
        float ua0 = 0.f, ua1 = 0.f, o0 = 0.f, o1 = 0.f;
        if (qtr == 0){
            ua0 = b2f(ub[cb + (size_t)li*ND + d0 + dg*2]);
            ua1 = b2f(ub[cb + (size_t)li*ND + d0 + dg*2 + 1]);
        }
        const int cbase = qtr*16;
        for (int ci=0; ci<16; ci++){
            const int cgi = cbase + ci;
            ushort4 wv4 = *(const ushort4*)&bw[li][cgi*4];
            ushort4 qv4 = *(const ushort4*)&bq[li][cgi*4];
            float4 wv = make_float4(us2f(wv4.x),us2f(wv4.y),us2f(wv4.z),us2f(wv4.w));
            float4 qv = make_float4(us2f(qv4.x),us2f(qv4.y),us2f(qv4.z),us2f(qv4.w));
            float4 s0 = *(const float4*)&St[dg*2+0][cgi*4];
            float4 s1 = *(const float4*)&St[dg*2+1][cgi*4];
            ua0 -= DOT4(wv, s0);  ua1 -= DOT4(wv, s1);
            o0  += DOT4(qv, s0);  o1  += DOT4(qv, s1);
        }
        uap[qtr][li][dg*2]   = ua0;
        uap[qtr][li][dg*2+1] = ua1;
        oap[qtr][li][dg*2]   = o0;
        oap[qtr][li][dg*2+1] = o1;
        __syncthreads();
        // combine partials (t < 512)
        float oc = 0.f;
        if (t < 512){
            float uav = uap[0][r1][c1] + uap[1][r1][c1] + uap[2][r1][c1] + uap[3][r1][c1];
            oc        = oap[0][r1][c1] + oap[1][r1][c1] + oap[2][r1][c1] + oap[3][r1][c1];
            ual[r1][c1] = uav;
        }
        __syncthreads();
        // phase1b: o += attn @ ua ; write path_delta (t < 512)
        if (t < 512){
            for (int j=0;j<32;j++) oc += atl[r1][j]*ual[j][c1];
            pdb[(size_t)(n*32 + r1)*ND + c1] = f2b(oc);
        }
        // update: St[dv][dk] += sum_j k[j][dk]*ua[j][dv]  (all 1024 threads, 1 dv row each)
        float4 sac = make_float4(0.f,0.f,0.f,0.f);
        for (int j=0;j<32;j++){
            ushort4 kv4 = *(const ushort4*)&bk[j][cg*4];
            float4 kv = make_float4(us2f(kv4.x),us2f(kv4.y),us2f(kv4.z),us2f(kv4.w));
            float u0 = ual[j][dh];
            sac.x += kv.x*u0; sac.y += kv.y*u0; sac.z += kv.z*u0; sac.w += kv.w*u0;
        }
        {
            float4* sp = (float4*)&St[dh][cg*4];
            float4 c0 = *sp;
            c0.x += sac.x; c0.y += sac.y; c0.z += sac.z; c0.w += sac.w;
            *sp = c0;
        }
    }
}

// ---------------- stats of 4 paths + gate_in assembly ----------------
__global__ __launch_bounds__(256) void gate_in_kernel(const float* __restrict__ hs,
    const bf16* __restrict__ ps, const bf16* __restrict__ pl,
    const bf16* __restrict__ pdl, const bf16* __restrict__ vc,
    bf16* __restrict__ gin)
{
    const int row = blockIdx.x;
    const int t = threadIdx.x;
    const int h = t >> 6, lane = t & 63;
    float4 hv = ld4f(hs + (size_t)row*ND + t*4);
    st4(gin + (size_t)row*1088 + t*4, hv);
    const size_t off = (size_t)row*ND + h*NDK + lane*4;
    const bf16* srcs[4] = {ps, pl, pdl, vc};
    #pragma unroll
    for (int p=0;p<4;p++){
        float4 v = ld4f(srcs[p] + off);
        float sx = v.x+v.y+v.z+v.w;
        float sq = v.x*v.x+v.y*v.y+v.z*v.z+v.w*v.w;
        float sa = fabsf(v.x)+fabsf(v.y)+fabsf(v.z)+fabsf(v.w);
        #pragma unroll
        for (int o=32;o>0;o>>=1){ sx+=__shfl_xor(sx,o); sq+=__shfl_xor(sq,o); sa+=__shfl_xor(sa,o); }
        if (lane==0){
            float mean = sx*(1.f/256.f);
            float var  = sq*(1.f/256.f) - mean*mean;
            bf16* o2 = gin + (size_t)row*1088 + 1024 + p*16 + h*4;
            o2[0]=f2b(mean); o2[1]=f2b(var); o2[2]=f2b(sa*(1.f/256.f)); o2[3]=f2b(sqrtf(sq));
        }
    }
}

// ---------------- logits -> softmax/tau -> floor -> weights ----------------
__global__ __launch_bounds__(256) void gate_weights_kernel(const bf16* __restrict__ h1,
    const float* __restrict__ W2, const float* __restrict__ b2,
    const float* __restrict__ log_temp, const float* __restrict__ fp,
    float* __restrict__ wt)
{
    __shared__ float part[16][17];
    __shared__ float lg[16];
    const int row = blockIdx.x, t = threadIdx.x;
    const int o = t >> 4, g = t & 15;
    const bf16* hr = h1 + (size_t)row*1024;
    const float* wr = W2 + (size_t)o*1024;
    float s = 0.f;
    for (int i2=0;i2<64;i2++){ int k = g + (i2<<4); s += b2f(hr[k])*wr[k]; }
    part[o][g] = s;
    __syncthreads();
    if (t < 16){
        float acc = b2[t];
        #pragma unroll
        for (int g2=0;g2<16;g2++) acc += part[t][g2];
        lg[t] = acc;
    }
    __syncthreads();
    if (t < 4){
        const int h = t;
        float x[4], fl[4];
        float mx = -1e30f;
        #pragma unroll
        for (int p=0;p<4;p++){
            float lt = log_temp[h*4+p];
            float tau = (lt > 20.f ? lt : log1pf(expf(lt))) + 0.25f;
            x[p] = lg[h*4+p] / tau;
            mx = fmaxf(mx, x[p]);
        }
        float se = 0.f;
        #pragma unroll
        for (int p=0;p<4;p++){ x[p] = expf(x[p]-mx); se += x[p]; }
        float sfl = 0.f;
        #pragma unroll
        for (int p=0;p<4;p++){
            fl[p] = fminf(0.005f + sigf(fp[h*4+p])*0.07f, 0.25f);
            sfl += fl[p];
        }
        float sf = fminf(sfl, 0.99f);
        float cs = 0.f;
        float cl[4];
        #pragma unroll
        for (int p=0;p<4;p++){
            float prob = x[p]/se;
            float nf = fl[p]/sf*0.99f;
            cl[p] = fmaxf(prob, nf + 1e-9f);
            cs += cl[p];
        }
        float inv = 1.f/(cs + 1e-8f);
        #pragma unroll
        for (int p=0;p<4;p++) wt[(size_t)row*16 + h*4 + p] = cl[p]*inv;
    }
}

// ---------------- mix 4 paths + per-head RMSNorm (om aliases vc; per-thread safe) ----------------
__global__ __launch_bounds__(256) void mix_kernel(const float* wt,
    const bf16* ps, const bf16* pl, const bf16* pdl, const bf16* vc,
    const float* onw, bf16* om)
{
    const int row = blockIdx.x, t = threadIdx.x;
    const int h = t >> 6, lane = t & 63;
    const size_t off = (size_t)row*ND + h*NDK + lane*4;
    const float w0 = wt[(size_t)row*16+h*4+0];
    const float w1 = wt[(size_t)row*16+h*4+1];
    const float w2 = wt[(size_t)row*16+h*4+2];
    const float w3 = wt[(size_t)row*16+h*4+3];
    float4 a = ld4f(ps+off);
    float4 b4 = ld4f(pl+off);
    float4 c = ld4f(pdl+off);
    float4 d = ld4f(vc+off);
    float4 o;
    o.x = w0*a.x + w1*b4.x + w2*c.x + w3*d.x;
    o.y = w0*a.y + w1*b4.y + w2*c.y + w3*d.y;
    o.z = w0*a.z + w1*b4.z + w2*c.z + w3*d.z;
    o.w = w0*a.w + w1*b4.w + w2*c.w + w3*d.w;
    float sq = o.x*o.x+o.y*o.y+o.z*o.z+o.w*o.w;
    #pragma unroll
    for (int oo=32;oo>0;oo>>=1) sq += __shfl_xor(sq,oo);
    float r = rsqrtf(sq*(1.f/256.f) + 1e-5f);
    float4 nw = *(const float4*)(onw + lane*4);
    o.x *= r*nw.x; o.y *= r*nw.y; o.z *= r*nw.z; o.w *= r*nw.w;
    st4(om+off, o);
}

extern "C" void kernel_launch(void* const* d_in, const int* in_sizes, int n_in,
                              void* d_out, int out_size, void* d_ws, size_t ws_size,
                              hipStream_t stream)
{
    const float* hs  = (const float*)d_in[0];
    const float* Wq  = (const float*)d_in[1];
    const float* Wk  = (const float*)d_in[2];
    const float* Wv  = (const float*)d_in[3];
    const float* Wbp = (const float*)d_in[4];
    const float* cq  = (const float*)d_in[5];
    const float* ck  = (const float*)d_in[6];
    const float* cv  = (const float*)d_in[7];
    const float* fsw = (const float*)d_in[8];
    const float* flw = (const float*)d_in[9];
    const float* log_temp = (const float*)d_in[10];
    const float* floor_p  = (const float*)d_in[11];
    const float* gW1 = (const float*)d_in[12];
    const float* gb1 = (const float*)d_in[13];
    const float* gW2 = (const float*)d_in[14];
    const float* gb2 = (const float*)d_in[15];
    const float* onw = (const float*)d_in[16];
    const float* Wo  = (const float*)d_in[17];

    const size_t NEEDED = 206831616ULL;
    if (ws_size < NEEDED) return;

    const size_t E = 16777216ULL;
    bf16* W = (bf16*)d_ws;
    bf16* B0 = W;            // proj scratch -> pdl
    bf16* B1 = W + E;        // q -> ps
    bf16* B2 = W + 2*E;      // k -> pl
    bf16* B3 = W + 3*E;      // v -> om (in place)
    bf16* B4 = W + 4*E;      // u ; then gin
    bf16* B5 = W + 5*E;      // w
    bf16* attnb = W + 6*E;                       // 2,097,152 elems (4MB)
    bf16* gin = B4;                              // 17,825,792 elems (after scan)
    bf16* h1  = B4 + 17825792;                   // 16,777,216 elems (ends inside dead attn)
    float* beta = (float*)((char*)d_ws + 205520896);
    float* wt   = (float*)((char*)d_ws + 205783040);
    float* ftc = (float*)attnb;                  // conv filters (K<=5), used BEFORE ut
    float* fts = (float*)attnb;                  // fir short (K=5), used AFTER scan
    float* ftl = (float*)attnb + 8192;           // fir long (K=63), used AFTER scan

    dim3 gg(8, 128);
    // projections + conv (+SiLU)  [full split: WS=1]
    gemm_mfma<float,0,1,bf16><<<gg,256,0,stream>>>(hs, Wq, nullptr, B0, 16384, 1024, 1024);
    ftrans_kernel<<<16,256,0,stream>>>(cq, ftc, 4);
    dwconv3_kernel<4,1><<<1024,256,0,stream>>>(B0, ftc, B1);
    gemm_mfma<float,0,1,bf16><<<gg,256,0,stream>>>(hs, Wk, nullptr, B0, 16384, 1024, 1024);
    ftrans_kernel<<<16,256,0,stream>>>(ck, ftc, 4);
    dwconv3_kernel<4,1><<<1024,256,0,stream>>>(B0, ftc, B2);
    gemm_mfma<float,0,1,bf16><<<gg,256,0,stream>>>(hs, Wv, nullptr, B0, 16384, 1024, 1024);
    ftrans_kernel<<<16,256,0,stream>>>(cv, ftc, 4);
    dwconv3_kernel<4,1><<<1024,256,0,stream>>>(B0, ftc, B3);
    beta_kernel<<<16384,256,0,stream>>>(hs, Wbp, beta);
    // l2norm q,k in place
    prep_kernel<<<16384,256,0,stream>>>(B1, B2);
    // UT transform: u=B4, w=B5 (overwrites ftc region with attn)
    ut_kernel<<<2048,256,0,stream>>>(B1, B2, B3, beta, B4, B5, attnb);
    // sequential scan -> path_delta = B0  (256 WGs x 1024 threads, 4 waves/SIMD, no spills)
    scan16f_kernel<<<256,1024,0,stream>>>(B1, B2, B4, B5, attnb, B0);
    // FIR paths from v (B3)
    ftrans_kernel<<<20,256,0,stream>>>(fsw, fts, 5);
    dwconv3_kernel<5,0><<<1024,256,0,stream>>>(B3, fts, B1);
    ftrans_kernel<<<252,256,0,stream>>>(flw, ftl, 63);
    dwconv3_kernel<63,0><<<1024,256,0,stream>>>(B3, ftl, B2);
    // gate  [post-recurrence: WS=0, single W product]
    gate_in_kernel<<<16384,256,0,stream>>>(hs, B1, B2, B0, B3, gin);
    gemm_mfma<bf16,1,0,bf16><<<gg,256,0,stream>>>(gin, gW1, gb1, h1, 16384, 1024, 1088);
    gate_weights_kernel<<<16384,256,0,stream>>>(h1, gW2, gb2, log_temp, floor_p, wt);
    // mix + RMSNorm (in place over B3)
    mix_kernel<<<16384,256,0,stream>>>(wt, B1, B2, B0, B3, onw, B3);
    // output projection -> f32 d_out  [WS=0]
    gemm_mfma<bf16,0,0,float><<<gg,256,0,stream>>>(B3, Wo, nullptr, (float*)d_out, 16384, 1024, 1024);
}

// Round 20
// 2613.035 us; speedup vs baseline: 1.3418x; 1.3418x over previous
//
#include <hip/hip_runtime.h>
#include <hip/hip_bf16.h>
#include <cstddef>

#define NB 4
#define NL 4096
#define ND 1024
#define NH 4
#define NDK 256
#define NCH 128

typedef __hip_bfloat16 bf16;
typedef __attribute__((ext_vector_type(8))) short bf16x8;
typedef __attribute__((ext_vector_type(4))) float f32x4;

__device__ __forceinline__ float sigf(float x){ return 1.0f/(1.0f + expf(-x)); }
__device__ __forceinline__ float geluf(float x){ return 0.5f*x*(1.0f+erff(x*0.70710678118654752f)); }
__device__ __forceinline__ float us2f(unsigned short s){ return __uint_as_float(((unsigned int)s)<<16); }
__device__ __forceinline__ float b2f(bf16 x){ return __bfloat162float(x); }
__device__ __forceinline__ bf16  f2b(float x){ return __float2bfloat16(x); }
__device__ __forceinline__ unsigned short f2bu(float x){ bf16 h = f2b(x); return *(unsigned short*)&h; }

__device__ __forceinline__ float4 ld4f(const float* p){ return *(const float4*)p; }
__device__ __forceinline__ float4 ld4f(const bf16* p){
    ushort4 u = *(const ushort4*)p;
    return make_float4(us2f(u.x), us2f(u.y), us2f(u.z), us2f(u.w));
}
__device__ __forceinline__ void st4(float* p, float4 v){ *(float4*)p = v; }
__device__ __forceinline__ void st4(bf16* p, float4 v){
    bf16 a=f2b(v.x), b=f2b(v.y), c=f2b(v.z), d=f2b(v.w);
    ushort4 u;
    u.x=*(unsigned short*)&a; u.y=*(unsigned short*)&b;
    u.z=*(unsigned short*)&c; u.w=*(unsigned short*)&d;
    *(ushort4*)p = u;
}

#define DOT4(v, s) ((v).x*(s).x + (v).y*(s).y + (v).z*(s).z + (v).w*(s).w)

// ---------------- MFMA GEMM with split-bf16 precision ----------------
// WS=1: W split hi+lo (2 W-products); WS=0: W hi only (1 product). X f32 adds xl*bh.
template<typename XT, int ACT, int WS, typename CT>
__global__ __launch_bounds__(256) void gemm_mfma(const XT* __restrict__ X,
    const float* __restrict__ W, const float* __restrict__ bias,
    CT* __restrict__ C, int M, int N, int K)
{
    constexpr int SX = (sizeof(XT)==4) ? 1 : 0;
    __shared__ unsigned short Ah[128*40];
    __shared__ unsigned short Al[SX ? 128*40 : 8];
    __shared__ unsigned short Bh[128*40];
    __shared__ unsigned short Bl[WS ? 128*40 : 8];
    const int t = threadIdx.x;
    const int wid = t >> 6, l = t & 63;
    const int wr = wid >> 1, wc = wid & 1;
    const int bm = blockIdx.y*128, bn = blockIdx.x*128;
    const int sr = t >> 1, sk = (t & 1)*16;
    const XT* Xb = X + (size_t)(bm+sr)*K + sk;
    const float* Wb = W + (size_t)(bn+sr)*K + sk;
    const int lr = l & 15, lk = (l >> 4)*8;
    f32x4 acc[4][4];
    #pragma unroll
    for (int i=0;i<4;i++)
        #pragma unroll
        for (int j=0;j<4;j++) acc[i][j] = (f32x4){0.f,0.f,0.f,0.f};

    for (int kt = 0; kt < K; kt += 32) {
        unsigned short hx[16], lx[16], hw[16], lw[16];
        {
            float wf[16];
            *(float4*)&wf[0]  = ld4f(Wb + kt);
            *(float4*)&wf[4]  = ld4f(Wb + kt + 4);
            *(float4*)&wf[8]  = ld4f(Wb + kt + 8);
            *(float4*)&wf[12] = ld4f(Wb + kt + 12);
            #pragma unroll
            for (int j=0;j<16;j++){
                bf16 h = f2b(wf[j]);
                hw[j] = *(unsigned short*)&h;
                if (WS) lw[j] = f2bu(wf[j] - b2f(h));
            }
        }
        if constexpr (SX){
            float xf[16];
            *(float4*)&xf[0]  = ld4f(Xb + kt);
            *(float4*)&xf[4]  = ld4f(Xb + kt + 4);
            *(float4*)&xf[8]  = ld4f(Xb + kt + 8);
            *(float4*)&xf[12] = ld4f(Xb + kt + 12);
            #pragma unroll
            for (int j=0;j<16;j++){
                bf16 h = f2b(xf[j]);
                hx[j] = *(unsigned short*)&h;
                lx[j] = f2bu(xf[j] - b2f(h));
            }
        } else {
            *(uint4*)&hx[0] = *(const uint4*)(Xb + kt);
            *(uint4*)&hx[8] = *(const uint4*)(Xb + kt + 8);
        }
        __syncthreads();
        *(uint4*)&Ah[sr*40 + sk]     = *(uint4*)&hx[0];
        *(uint4*)&Ah[sr*40 + sk + 8] = *(uint4*)&hx[8];
        if constexpr (SX){
            *(uint4*)&Al[sr*40 + sk]     = *(uint4*)&lx[0];
            *(uint4*)&Al[sr*40 + sk + 8] = *(uint4*)&lx[8];
        }
        *(uint4*)&Bh[sr*40 + sk]     = *(uint4*)&hw[0];
        *(uint4*)&Bh[sr*40 + sk + 8] = *(uint4*)&hw[8];
        if constexpr (WS){
            *(uint4*)&Bl[sr*40 + sk]     = *(uint4*)&lw[0];
            *(uint4*)&Bl[sr*40 + sk + 8] = *(uint4*)&lw[8];
        }
        __syncthreads();
        bf16x8 ah[4], al[4];
        #pragma unroll
        for (int mi=0;mi<4;mi++){
            ah[mi] = *(const bf16x8*)&Ah[(wr*64 + mi*16 + lr)*40 + lk];
            if constexpr (SX) al[mi] = *(const bf16x8*)&Al[(wr*64 + mi*16 + lr)*40 + lk];
        }
        #pragma unroll
        for (int nj=0;nj<4;nj++){
            bf16x8 bh = *(const bf16x8*)&Bh[(wc*64 + nj*16 + lr)*40 + lk];
            bf16x8 bl;
            if constexpr (WS) bl = *(const bf16x8*)&Bl[(wc*64 + nj*16 + lr)*40 + lk];
            #pragma unroll
            for (int mi=0;mi<4;mi++){
                acc[mi][nj] = __builtin_amdgcn_mfma_f32_16x16x32_bf16(ah[mi], bh, acc[mi][nj], 0,0,0);
                if constexpr (WS)
                    acc[mi][nj] = __builtin_amdgcn_mfma_f32_16x16x32_bf16(ah[mi], bl, acc[mi][nj], 0,0,0);
                if constexpr (SX)
                    acc[mi][nj] = __builtin_amdgcn_mfma_f32_16x16x32_bf16(al[mi], bh, acc[mi][nj], 0,0,0);
            }
        }
    }
    const int cr0 = (l >> 4) * 4;
    #pragma unroll
    for (int nj=0;nj<4;nj++){
        const int col = bn + wc*64 + nj*16 + lr;
        const float bv = bias ? bias[col] : 0.f;
        #pragma unroll
        for (int mi=0;mi<4;mi++){
            const int m0 = bm + wr*64 + mi*16 + cr0;
            #pragma unroll
            for (int r=0;r<4;r++){
                float v = acc[mi][nj][r] + bv;
                if (ACT==1) v = geluf(v);
                if constexpr (sizeof(CT)==2) C[(size_t)(m0+r)*N + col] = f2b(v);
                else                         C[(size_t)(m0+r)*N + col] = v;
            }
        }
    }
}

// ---------------- filter transpose: f[c][k] -> ft[k][c] ----------------
__global__ __launch_bounds__(256) void ftrans_kernel(const float* __restrict__ f,
    float* __restrict__ ft, int K)
{
    int idx = blockIdx.x*256 + threadIdx.x;
    if (idx < ND*K){
        int c = idx / K, k = idx - c*K;
        ft[k*ND + c] = f[idx];
    }
}

// ---------------- depthwise causal conv: reg sliding window, 8 rows x 8 ch / thread ----------------
template<int K, int ACT>
__global__ __launch_bounds__(256) void dwconv3_kernel(const bf16* __restrict__ x,
    const float* __restrict__ ft, bf16* __restrict__ y)
{
    const int tr = threadIdx.x >> 7;
    const int c8 = (threadIdx.x & 127) * 8;
    const long row0 = (long)blockIdx.x * 16 + tr * 8;
    const int l0 = (int)(row0 & (NL - 1));
    const long bbase = row0 - l0;
    float xw[8][8];
    float acc[8][8];
    #pragma unroll
    for (int r=0;r<8;r++)
        #pragma unroll
        for (int j=0;j<8;j++) acc[r][j] = 0.f;
    #pragma unroll
    for (int w2=0;w2<8;w2++){
        int ls = l0 - (K-1) + w2;
        if (ls >= 0){
            const bf16* p = x + (bbase + ls)*ND + c8;
            ushort4 lo = *(const ushort4*)p;
            ushort4 hi = *(const ushort4*)(p + 4);
            xw[w2][0]=us2f(lo.x); xw[w2][1]=us2f(lo.y); xw[w2][2]=us2f(lo.z); xw[w2][3]=us2f(lo.w);
            xw[w2][4]=us2f(hi.x); xw[w2][5]=us2f(hi.y); xw[w2][6]=us2f(hi.z); xw[w2][7]=us2f(hi.w);
        } else {
            #pragma unroll
            for (int j=0;j<8;j++) xw[w2][j]=0.f;
        }
    }
    #pragma unroll
    for (int tt=0;tt<K;tt++){
        float4 f0 = *(const float4*)(ft + (size_t)tt*ND + c8);
        float4 f1 = *(const float4*)(ft + (size_t)tt*ND + c8 + 4);
        float fv[8] = {f0.x,f0.y,f0.z,f0.w,f1.x,f1.y,f1.z,f1.w};
        #pragma unroll
        for (int r=0;r<8;r++){
            const int sl = (tt + r) & 7;
            #pragma unroll
            for (int j=0;j<8;j++) acc[r][j] += xw[sl][j]*fv[j];
        }
        if (tt < K-1){
            const int sl = tt & 7;
            int ls = l0 - (K-1) + tt + 8;
            if (ls >= 0){
                const bf16* p = x + (bbase + ls)*ND + c8;
                ushort4 lo = *(const ushort4*)p;
                ushort4 hi = *(const ushort4*)(p + 4);
                xw[sl][0]=us2f(lo.x); xw[sl][1]=us2f(lo.y); xw[sl][2]=us2f(lo.z); xw[sl][3]=us2f(lo.w);
                xw[sl][4]=us2f(hi.x); xw[sl][5]=us2f(hi.y); xw[sl][6]=us2f(hi.z); xw[sl][7]=us2f(hi.w);
            } else {
                #pragma unroll
                for (int j=0;j<8;j++) xw[sl][j]=0.f;
            }
        }
    }
    #pragma unroll
    for (int r=0;r<8;r++){
        bf16* yp = y + (bbase + l0 + r)*ND + c8;
        float o[8];
        #pragma unroll
        for (int j=0;j<8;j++){
            float v = acc[r][j];
            if (ACT) v = v * sigf(v);
            o[j] = v;
        }
        st4(yp,   make_float4(o[0],o[1],o[2],o[3]));
        st4(yp+4, make_float4(o[4],o[5],o[6],o[7]));
    }
}

// ---------------- beta = sigmoid(hs @ Wb^T) ----------------
__global__ __launch_bounds__(256) void beta_kernel(const float* __restrict__ hs,
    const float* __restrict__ Wb, float* __restrict__ beta)
{
    const int wid = (int)((blockIdx.x*256 + threadIdx.x) >> 6);
    const int lane = threadIdx.x & 63;
    const int h = wid & 3, row = wid >> 2;
    const float* x = hs + (size_t)row*ND;
    const float* w = Wb + (size_t)h*ND;
    float s = 0.f;
    for (int i = lane; i < ND; i += 64) s += x[i]*w[i];
    #pragma unroll
    for (int o=32;o>0;o>>=1) s += __shfl_xor(s,o);
    if (lane == 0) beta[(size_t)row*NH + h] = sigf(s);
}

// ---------------- l2norm q,k in place ----------------
__global__ __launch_bounds__(256) void prep_kernel(bf16* __restrict__ q, bf16* __restrict__ k)
{
    const int row = blockIdx.x;
    const int h = threadIdx.x >> 6, lane = threadIdx.x & 63;
    const size_t off = (size_t)row*ND + h*NDK + lane*4;
    float4 q4 = ld4f(q + off);
    float4 k4 = ld4f(k + off);
    float sq = q4.x*q4.x+q4.y*q4.y+q4.z*q4.z+q4.w*q4.w;
    float sk = k4.x*k4.x+k4.y*k4.y+k4.z*k4.z+k4.w*k4.w;
    #pragma unroll
    for (int o=32;o>0;o>>=1){ sq += __shfl_xor(sq,o); sk += __shfl_xor(sk,o); }
    float rq = rsqrtf(sq + 1e-6f), rk = rsqrtf(sk + 1e-6f);
    q4.x*=rq; q4.y*=rq; q4.z*=rq; q4.w*=rq;
    k4.x*=rk; k4.y*=rk; k4.z*=rk; k4.w*=rk;
    st4(q + off, q4);
    st4(k + off, k4);
}

// ---------------- UT transform per (b,h,chunk) ----------------
__global__ __launch_bounds__(256) void ut_kernel(const bf16* __restrict__ qn,
    const bf16* __restrict__ kn, const bf16* __restrict__ vv,
    const float* __restrict__ beta, bf16* __restrict__ u_,
    bf16* __restrict__ w_, bf16* __restrict__ attn)
{
    __shared__ float ks[32][257];
    __shared__ float qs[32][257];
    __shared__ float dkk[32][33];
    __shared__ float Ti[32][33];
    __shared__ float bs[32];
    const int blk = blockIdx.x;
    const int n = blk & (NCH-1), bh = blk >> 7;
    const int b = bh >> 2, h = bh & 3;
    const int t = threadIdx.x;
    const size_t base = ((size_t)b*NL + n*32)*ND + h*NDK;
    #pragma unroll
    for (int r=0;r<8;r++){
        int idx = t + (r<<8);
        int i = idx >> 6, dp = (idx & 63) << 2;
        float4 kv = ld4f(kn + base + (size_t)i*ND + dp);
        ks[i][dp]=kv.x; ks[i][dp+1]=kv.y; ks[i][dp+2]=kv.z; ks[i][dp+3]=kv.w;
        float4 qv = ld4f(qn + base + (size_t)i*ND + dp);
        qs[i][dp]=qv.x; qs[i][dp+1]=qv.y; qs[i][dp+2]=qv.z; qs[i][dp+3]=qv.w;
    }
    if (t < 32) bs[t] = beta[((size_t)b*NL + n*32 + t)*NH + h];
    __syncthreads();
    #pragma unroll
    for (int p=0;p<4;p++){
        const int i = (t>>5) + (p<<3), j = t & 31;
        float aK=0.f, aA=0.f;
        for (int d2=0; d2<256; d2++){
            float kj = ks[j][d2];
            aK += ks[i][d2]*kj;
            aA += qs[i][d2]*kj;
        }
        dkk[i][j] = aK;
        attn[((size_t)bh*NCH + n)*1024 + i*32 + j] = f2b((j<=i)? aA : 0.f);
    }
    __syncthreads();
    if (t < 32) Ti[0][t] = (t==0)?1.f:0.f;
    __syncthreads();
    for (int i=1;i<32;i++){
        if (t < 32){
            const int j = t;
            float v;
            if (j > i) v = 0.f;
            else if (j == i) v = 1.f;
            else {
                float acc = 0.f;
                for (int p2=j;p2<i;p2++) acc += dkk[i][p2]*Ti[p2][j];
                v = -bs[i]*acc;
            }
            Ti[i][j] = v;
        }
        __syncthreads();
    }
    {
        float ua[32];
        #pragma unroll
        for (int i=0;i<32;i++) ua[i]=0.f;
        for (int j=0;j<32;j++){
            float vj = b2f(vv[base + (size_t)j*ND + t]) * bs[j];
            #pragma unroll
            for (int i=0;i<32;i++) ua[i] += Ti[i][j]*vj;
        }
        #pragma unroll
        for (int i=0;i<32;i++) u_[base + (size_t)i*ND + t] = f2b(ua[i]);
        #pragma unroll
        for (int i=0;i<32;i++) ua[i]=0.f;
        for (int j=0;j<32;j++){
            float kjv = ks[j][t]*bs[j];
            #pragma unroll
            for (int i=0;i<32;i++) ua[i] += Ti[i][j]*kjv;
        }
        #pragma unroll
        for (int i=0;i<32;i++) w_[base + (size_t)i*ND + t] = f2b(ua[i]);
    }
}

// ---------------- sequential chunk scan: slice 16, 256 WGs x 512 threads (round-13 best) ----------------
__global__ __launch_bounds__(512) void scan16c_kernel(const bf16* __restrict__ qn,
    const bf16* __restrict__ kn, const bf16* __restrict__ u_,
    const bf16* __restrict__ w_, const bf16* __restrict__ attn,
    bf16* __restrict__ pd)
{
    __shared__ unsigned short bw[32][268];
    __shared__ unsigned short bq[32][268];
    __shared__ unsigned short bk[32][268];
    __shared__ float St[16][260];            // S transposed: [dv_local][dk]
    __shared__ float ual[32][21];            // combined u_adj [c][dv_local]
    __shared__ float uap[2][32][21];         // partials
    __shared__ float oap[2][32][21];
    __shared__ float atl[32][33];
    const int blk = blockIdx.x;              // 256 WGs
    const int sl = blk >> 4;                 // dv slice 0..15
    const int bh = blk & 15;                 // same-bh WGs share XCD
    const int b = bh >> 2, h = bh & 3;
    const int d0 = sl * 16;
    const int t = threadIdx.x;               // 0..511
    const int half = t >> 8;                 // k-range half
    const int tt = t & 255;
    const int li = tt & 31, dg = tt >> 5;    // phase1: row li, dv cols dg*2, dg*2+1
    const int r1 = t >> 4, c1 = t & 15;      // combine/phase1b: (row, dv col)
    const int cg = t & 63, dh = t >> 6;      // update: dk cols cg*4..+3, dv rows dh*2, dh*2+1
    for (int i = t; i < 16*260; i += 512) ((float*)St)[i] = 0.f;
    const bf16* qb = qn + (size_t)b*NL*ND + h*NDK;
    const bf16* kb = kn + (size_t)b*NL*ND + h*NDK;
    const bf16* ub = u_ + (size_t)b*NL*ND + h*NDK;
    const bf16* wb = w_ + (size_t)b*NL*ND + h*NDK;
    const bf16* ab = attn + (size_t)bh*NCH*1024;
    bf16* pdb = pd + (size_t)b*NL*ND + h*NDK + d0;
    for (int n=0;n<NCH;n++){
        const size_t cb = (size_t)n*32*ND;
        __syncthreads();   // prev consumers done before restage
        #pragma unroll
        for (int it=0;it<4;++it){
            int idx = it*512 + t;
            int row = idx >> 6, c4 = (idx & 63)*4;
            *(ushort4*)&bw[row][c4] = *(const ushort4*)&wb[cb + (size_t)row*ND + c4];
            *(ushort4*)&bq[row][c4] = *(const ushort4*)&qb[cb + (size_t)row*ND + c4];
            *(ushort4*)&bk[row][c4] = *(const ushort4*)&kb[cb + (size_t)row*ND + c4];
        }
        #pragma unroll
        for (int r=0;r<2;r++){ int idx = t + (r<<9); atl[idx>>5][idx&31] = b2f(ab[(size_t)n*1024 + idx]); }
        __syncthreads();
        // phase1 partial: half 0 -> cgi 0..31 (seeds with u), half 1 -> cgi 32..63
        float ua0 = 0.f, ua1 = 0.f, o0 = 0.f, o1 = 0.f;
        if (half == 0){
            ua0 = b2f(ub[cb + (size_t)li*ND + d0 + dg*2]);
            ua1 = b2f(ub[cb + (size_t)li*ND + d0 + dg*2 + 1]);
        }
        const int cbase = half*32;
        for (int ci=0; ci<32; ci++){
            const int cgi = cbase + ci;
            ushort4 wv4 = *(const ushort4*)&bw[li][cgi*4];
            ushort4 qv4 = *(const ushort4*)&bq[li][cgi*4];
            float4 wv = make_float4(us2f(wv4.x),us2f(wv4.y),us2f(wv4.z),us2f(wv4.w));
            float4 qv = make_float4(us2f(qv4.x),us2f(qv4.y),us2f(qv4.z),us2f(qv4.w));
            float4 s0 = *(const float4*)&St[dg*2+0][cgi*4];
            float4 s1 = *(const float4*)&St[dg*2+1][cgi*4];
            ua0 -= DOT4(wv, s0);  ua1 -= DOT4(wv, s1);
            o0  += DOT4(qv, s0);  o1  += DOT4(qv, s1);
        }
        uap[half][li][dg*2]   = ua0;
        uap[half][li][dg*2+1] = ua1;
        oap[half][li][dg*2]   = o0;
        oap[half][li][dg*2+1] = o1;
        __syncthreads();
        // combine partials
        float oc = oap[0][r1][c1] + oap[1][r1][c1];
        ual[r1][c1] = uap[0][r1][c1] + uap[1][r1][c1];
        __syncthreads();
        // phase1b: o += attn @ ua ; write path_delta
        for (int j=0;j<32;j++) oc += atl[r1][j]*ual[j][c1];
        pdb[(size_t)(n*32 + r1)*ND + c1] = f2b(oc);
        // update: St[dv][dk] += sum_j k[j][dk]*ua[j][dv]  (2 dv rows per thread)
        float4 sac0 = make_float4(0.f,0.f,0.f,0.f);
        float4 sac1 = make_float4(0.f,0.f,0.f,0.f);
        for (int j=0;j<32;j++){
            ushort4 kv4 = *(const ushort4*)&bk[j][cg*4];
            float4 kv = make_float4(us2f(kv4.x),us2f(kv4.y),us2f(kv4.z),us2f(kv4.w));
            float u0 = ual[j][dh*2];
            float u1 = ual[j][dh*2+1];
            sac0.x += kv.x*u0; sac0.y += kv.y*u0; sac0.z += kv.z*u0; sac0.w += kv.w*u0;
            sac1.x += kv.x*u1; sac1.y += kv.y*u1; sac1.z += kv.z*u1; sac1.w += kv.w*u1;
        }
        {
            float4* sp0 = (float4*)&St[dh*2+0][cg*4];
            float4 c0 = *sp0;
            c0.x += sac0.x; c0.y += sac0.y; c0.z += sac0.z; c0.w += sac0.w;
            *sp0 = c0;
            float4* sp1 = (float4*)&St[dh*2+1][cg*4];
            float4 cc1 = *sp1;
            cc1.x += sac1.x; cc1.y += sac1.y; cc1.z += sac1.z; cc1.w += sac1.w;
            *sp1 = cc1;
        }
    }
}

// ---------------- stats of 4 paths + gate_in assembly ----------------
__global__ __launch_bounds__(256) void gate_in_kernel(const float* __restrict__ hs,
    const bf16* __restrict__ ps, const bf16* __restrict__ pl,
    const bf16* __restrict__ pdl, const bf16* __restrict__ vc,
    bf16* __restrict__ gin)
{
    const int row = blockIdx.x;
    const int t = threadIdx.x;
    const int h = t >> 6, lane = t & 63;
    float4 hv = ld4f(hs + (size_t)row*ND + t*4);
    st4(gin + (size_t)row*1088 + t*4, hv);
    const size_t off = (size_t)row*ND + h*NDK + lane*4;
    const bf16* srcs[4] = {ps, pl, pdl, vc};
    #pragma unroll
    for (int p=0;p<4;p++){
        float4 v = ld4f(srcs[p] + off);
        float sx = v.x+v.y+v.z+v.w;
        float sq = v.x*v.x+v.y*v.y+v.z*v.z+v.w*v.w;
        float sa = fabsf(v.x)+fabsf(v.y)+fabsf(v.z)+fabsf(v.w);
        #pragma unroll
        for (int o=32;o>0;o>>=1){ sx+=__shfl_xor(sx,o); sq+=__shfl_xor(sq,o); sa+=__shfl_xor(sa,o); }
        if (lane==0){
            float mean = sx*(1.f/256.f);
            float var  = sq*(1.f/256.f) - mean*mean;
            bf16* o2 = gin + (size_t)row*1088 + 1024 + p*16 + h*4;
            o2[0]=f2b(mean); o2[1]=f2b(var); o2[2]=f2b(sa*(1.f/256.f)); o2[3]=f2b(sqrtf(sq));
        }
    }
}

// ---------------- logits -> softmax/tau -> floor -> weights ----------------
__global__ __launch_bounds__(256) void gate_weights_kernel(const bf16* __restrict__ h1,
    const float* __restrict__ W2, const float* __restrict__ b2,
    const float* __restrict__ log_temp, const float* __restrict__ fp,
    float* __restrict__ wt)
{
    __shared__ float part[16][17];
    __shared__ float lg[16];
    const int row = blockIdx.x, t = threadIdx.x;
    const int o = t >> 4, g = t & 15;
    const bf16* hr = h1 + (size_t)row*1024;
    const float* wr = W2 + (size_t)o*1024;
    float s = 0.f;
    for (int i2=0;i2<64;i2++){ int k = g + (i2<<4); s += b2f(hr[k])*wr[k]; }
    part[o][g] = s;
    __syncthreads();
    if (t < 16){
        float acc = b2[t];
        #pragma unroll
        for (int g2=0;g2<16;g2++) acc += part[t][g2];
        lg[t] = acc;
    }
    __syncthreads();
    if (t < 4){
        const int h = t;
        float x[4], fl[4];
        float mx = -1e30f;
        #pragma unroll
        for (int p=0;p<4;p++){
            float lt = log_temp[h*4+p];
            float tau = (lt > 20.f ? lt : log1pf(expf(lt))) + 0.25f;
            x[p] = lg[h*4+p] / tau;
            mx = fmaxf(mx, x[p]);
        }
        float se = 0.f;
        #pragma unroll
        for (int p=0;p<4;p++){ x[p] = expf(x[p]-mx); se += x[p]; }
        float sfl = 0.f;
        #pragma unroll
        for (int p=0;p<4;p++){
            fl[p] = fminf(0.005f + sigf(fp[h*4+p])*0.07f, 0.25f);
            sfl += fl[p];
        }
        float sf = fminf(sfl, 0.99f);
        float cs = 0.f;
        float cl[4];
        #pragma unroll
        for (int p=0;p<4;p++){
            float prob = x[p]/se;
            float nf = fl[p]/sf*0.99f;
            cl[p] = fmaxf(prob, nf + 1e-9f);
            cs += cl[p];
        }
        float inv = 1.f/(cs + 1e-8f);
        #pragma unroll
        for (int p=0;p<4;p++) wt[(size_t)row*16 + h*4 + p] = cl[p]*inv;
    }
}

// ---------------- mix 4 paths + per-head RMSNorm (om aliases vc; per-thread safe) ----------------
__global__ __launch_bounds__(256) void mix_kernel(const float* wt,
    const bf16* ps, const bf16* pl, const bf16* pdl, const bf16* vc,
    const float* onw, bf16* om)
{
    const int row = blockIdx.x, t = threadIdx.x;
    const int h = t >> 6, lane = t & 63;
    const size_t off = (size_t)row*ND + h*NDK + lane*4;
    const float w0 = wt[(size_t)row*16+h*4+0];
    const float w1 = wt[(size_t)row*16+h*4+1];
    const float w2 = wt[(size_t)row*16+h*4+2];
    const float w3 = wt[(size_t)row*16+h*4+3];
    float4 a = ld4f(ps+off);
    float4 b4 = ld4f(pl+off);
    float4 c = ld4f(pdl+off);
    float4 d = ld4f(vc+off);
    float4 o;
    o.x = w0*a.x + w1*b4.x + w2*c.x + w3*d.x;
    o.y = w0*a.y + w1*b4.y + w2*c.y + w3*d.y;
    o.z = w0*a.z + w1*b4.z + w2*c.z + w3*d.z;
    o.w = w0*a.w + w1*b4.w + w2*c.w + w3*d.w;
    float sq = o.x*o.x+o.y*o.y+o.z*o.z+o.w*o.w;
    #pragma unroll
    for (int oo=32;oo>0;oo>>=1) sq += __shfl_xor(sq,oo);
    float r = rsqrtf(sq*(1.f/256.f) + 1e-5f);
    float4 nw = *(const float4*)(onw + lane*4);
    o.x *= r*nw.x; o.y *= r*nw.y; o.z *= r*nw.z; o.w *= r*nw.w;
    st4(om+off, o);
}

extern "C" void kernel_launch(void* const* d_in, const int* in_sizes, int n_in,
                              void* d_out, int out_size, void* d_ws, size_t ws_size,
                              hipStream_t stream)
{
    const float* hs  = (const float*)d_in[0];
    const float* Wq  = (const float*)d_in[1];
    const float* Wk  = (const float*)d_in[2];
    const float* Wv  = (const float*)d_in[3];
    const float* Wbp = (const float*)d_in[4];
    const float* cq  = (const float*)d_in[5];
    const float* ck  = (const float*)d_in[6];
    const float* cv  = (const float*)d_in[7];
    const float* fsw = (const float*)d_in[8];
    const float* flw = (const float*)d_in[9];
    const float* log_temp = (const float*)d_in[10];
    const float* floor_p  = (const float*)d_in[11];
    const float* gW1 = (const float*)d_in[12];
    const float* gb1 = (const float*)d_in[13];
    const float* gW2 = (const float*)d_in[14];
    const float* gb2 = (const float*)d_in[15];
    const float* onw = (const float*)d_in[16];
    const float* Wo  = (const float*)d_in[17];

    const size_t NEEDED = 206831616ULL;
    if (ws_size < NEEDED) return;

    const size_t E = 16777216ULL;
    bf16* W = (bf16*)d_ws;
    bf16* B0 = W;            // proj scratch -> pdl
    bf16* B1 = W + E;        // q -> ps
    bf16* B2 = W + 2*E;      // k -> pl
    bf16* B3 = W + 3*E;      // v -> om (in place)
    bf16* B4 = W + 4*E;      // u ; then gin
    bf16* B5 = W + 5*E;      // w
    bf16* attnb = W + 6*E;                       // 2,097,152 elems (4MB)
    bf16* gin = B4;                              // 17,825,792 elems (after scan)
    bf16* h1  = B4 + 17825792;                   // 16,777,216 elems (ends inside dead attn)
    float* beta = (float*)((char*)d_ws + 205520896);
    float* wt   = (float*)((char*)d_ws + 205783040);
    float* ftc = (float*)attnb;                  // conv filters (K<=5), used BEFORE ut
    float* fts = (float*)attnb;                  // fir short (K=5), used AFTER scan
    float* ftl = (float*)attnb + 8192;           // fir long (K=63), used AFTER scan

    dim3 gg(8, 128);
    // projections + conv (+SiLU)  [full split: WS=1]
    gemm_mfma<float,0,1,bf16><<<gg,256,0,stream>>>(hs, Wq, nullptr, B0, 16384, 1024, 1024);
    ftrans_kernel<<<16,256,0,stream>>>(cq, ftc, 4);
    dwconv3_kernel<4,1><<<1024,256,0,stream>>>(B0, ftc, B1);
    gemm_mfma<float,0,1,bf16><<<gg,256,0,stream>>>(hs, Wk, nullptr, B0, 16384, 1024, 1024);
    ftrans_kernel<<<16,256,0,stream>>>(ck, ftc, 4);
    dwconv3_kernel<4,1><<<1024,256,0,stream>>>(B0, ftc, B2);
    gemm_mfma<float,0,1,bf16><<<gg,256,0,stream>>>(hs, Wv, nullptr, B0, 16384, 1024, 1024);
    ftrans_kernel<<<16,256,0,stream>>>(cv, ftc, 4);
    dwconv3_kernel<4,1><<<1024,256,0,stream>>>(B0, ftc, B3);
    beta_kernel<<<16384,256,0,stream>>>(hs, Wbp, beta);
    // l2norm q,k in place
    prep_kernel<<<16384,256,0,stream>>>(B1, B2);
    // UT transform: u=B4, w=B5 (overwrites ftc region with attn)
    ut_kernel<<<2048,256,0,stream>>>(B1, B2, B3, beta, B4, B5, attnb);
    // sequential scan -> path_delta = B0  (round-13 best variant)
    scan16c_kernel<<<256,512,0,stream>>>(B1, B2, B4, B5, attnb, B0);
    // FIR paths from v (B3)
    ftrans_kernel<<<20,256,0,stream>>>(fsw, fts, 5);
    dwconv3_kernel<5,0><<<1024,256,0,stream>>>(B3, fts, B1);
    ftrans_kernel<<<252,256,0,stream>>>(flw, ftl, 63);
    dwconv3_kernel<63,0><<<1024,256,0,stream>>>(B3, ftl, B2);
    // gate  [post-recurrence: WS=0, single W product]
    gate_in_kernel<<<16384,256,0,stream>>>(hs, B1, B2, B0, B3, gin);
    gemm_mfma<bf16,1,0,bf16><<<gg,256,0,stream>>>(gin, gW1, gb1, h1, 16384, 1024, 1088);
    gate_weights_kernel<<<16384,256,0,stream>>>(h1, gW2, gb2, log_temp, floor_p, wt);
    // mix + RMSNorm (in place over B3)
    mix_kernel<<<16384,256,0,stream>>>(wt, B1, B2, B0, B3, onw, B3);
    // output projection -> f32 d_out  [WS=0]
    gemm_mfma<bf16,0,0,float><<<gg,256,0,stream>>>(B3, Wo, nullptr, (float*)d_out, 16384, 1024, 1024);
}